// Round 4
// baseline (60.820 us; speedup 1.0000x reference)
//
#include <hip/hip_runtime.h>

#define SEQ_LEN 131072
#define D_MODEL 512
#define M_SIZE  1000
#define BETA    0.5f

typedef float f32x4 __attribute__((ext_vector_type(4)));

// ---------------------------------------------------------------------------
// Transpose W_m [D_MODEL][M] -> W_mT [M][D_MODEL] (2 MB, L2-resident) so the
// per-row gather in the main kernel is contiguous float4 loads.
// ---------------------------------------------------------------------------
__global__ void transpose_wm_kernel(const float* __restrict__ W_m,
                                    float* __restrict__ W_mT) {
    __shared__ float tile[32][33];  // +1 pad: no LDS bank conflicts
    const int bx = blockIdx.x;      // tile along M
    const int by = blockIdx.y;      // tile along D
    const int tx = threadIdx.x;     // 0..31
    const int ty = threadIdx.y;     // 0..7

    const int m = bx * 32 + tx;
    const int d0 = by * 32;
    for (int i = ty; i < 32; i += 8) {
        const int d = d0 + i;
        tile[i][tx] = (m < M_SIZE) ? W_m[(long)d * M_SIZE + m] : 0.0f;
    }
    __syncthreads();
    const int m0 = bx * 32;
    for (int i = ty; i < 32; i += 8) {
        const int mm = m0 + i;
        if (mm < M_SIZE) W_mT[(long)mm * D_MODEL + d0 + tx] = tile[tx][i];
    }
}

// ---------------------------------------------------------------------------
// Main kernel. Thread owns fixed float4 slot c = tid&127; grid-strides rows.
// 2048 blocks x 2 rows x 32 iters == 131072 rows exactly.
// Software pipeline: t/marker prefetched 2 iters ahead, the dependent W_mT
// GATHER prefetched 1 iter ahead -> no exposed L2 latency in steady state.
// NT stores keep the 2 MB W_mT table resident in L2 under the write stream.
// ---------------------------------------------------------------------------
#define SSTRIDE 4096   // gridDim.x(2048) * 2 rows/block
#define NITER   32     // SEQ_LEN / SSTRIDE

__global__ __launch_bounds__(256) void
embed_kernel(const float* __restrict__ t,
             const int* __restrict__ marker,
             const float* __restrict__ W_mT,
             const float* __restrict__ W_t,
             const float* __restrict__ b_t,
             float* __restrict__ out) {
    const int c = threadIdx.x & 127;          // float4 slot within row
    const int rowInBlock = threadIdx.x >> 7;  // 0 or 1
    int s = (int)blockIdx.x * 2 + rowInBlock;

    const f32x4 w = reinterpret_cast<const f32x4*>(W_t)[c];
    const f32x4 b = reinterpret_cast<const f32x4*>(b_t)[c];
    f32x4* __restrict__ out4 = reinterpret_cast<f32x4*>(out);
    const f32x4* __restrict__ wmT4 = reinterpret_cast<const f32x4*>(W_mT);

    // pipeline prologue: scalars for iters 0 and 1, gather for iter 0
    float t0 = t[s];            int m0 = marker[s];
    float t1 = t[s + SSTRIDE];  int m1 = marker[s + SSTRIDE];

    f32x4 em0 = (f32x4)(0.0f);
    if (t0 >= 0.0f) em0 = wmT4[(size_t)m0 * (D_MODEL / 4) + c];

    #pragma unroll 4
    for (int i = 0; i < NITER; ++i) {
        // prefetch scalars for iter i+2
        float t2 = 0.0f; int m2 = 0;
        if (i < NITER - 2) {
            const int s2 = s + 2 * SSTRIDE;
            t2 = t[s2];
            m2 = marker[s2];
        }
        // prefetch gather for iter i+1 (branch is wave-uniform: whole wave
        // covers one row)
        f32x4 em1 = (f32x4)(0.0f);
        if (i < NITER - 1 && t1 >= 0.0f)
            em1 = wmT4[(size_t)m1 * (D_MODEL / 4) + c];

        // compute + store iter i
        f32x4 o = (f32x4)(0.0f);
        if (t0 >= 0.0f) {
            o.x = BETA * em0.x + (1.0f - BETA) * fmaf(t0, w.x, b.x);
            o.y = BETA * em0.y + (1.0f - BETA) * fmaf(t0, w.y, b.y);
            o.z = BETA * em0.z + (1.0f - BETA) * fmaf(t0, w.z, b.z);
            o.w = BETA * em0.w + (1.0f - BETA) * fmaf(t0, w.w, b.w);
        }
        __builtin_nontemporal_store(o, out4 + (size_t)s * (D_MODEL / 4) + c);

        // rotate pipeline
        s += SSTRIDE;
        t0 = t1; em0 = em1;
        t1 = t2; m1 = m2;
        (void)m0; m0 = m1;
    }
}

extern "C" void kernel_launch(void* const* d_in, const int* in_sizes, int n_in,
                              void* d_out, int out_size, void* d_ws, size_t ws_size,
                              hipStream_t stream) {
    const float* t      = (const float*)d_in[0];
    const int*   marker = (const int*)d_in[1];
    const float* W_m    = (const float*)d_in[2];
    const float* W_t    = (const float*)d_in[3];
    const float* b_t    = (const float*)d_in[4];
    float* out = (float*)d_out;

    float* W_mT = (float*)d_ws;
    (void)ws_size;

    dim3 tgrid((M_SIZE + 31) / 32, D_MODEL / 32);  // 32 x 16
    dim3 tblock(32, 8);
    transpose_wm_kernel<<<tgrid, tblock, 0, stream>>>(W_m, W_mT);

    embed_kernel<<<2048, 256, 0, stream>>>(t, marker, W_mT, W_t, b_t, out);
}